// Round 1
// baseline (581.275 us; speedup 1.0000x reference)
//
#include <hip/hip_runtime.h>
#include <hip/hip_bf16.h>

typedef _Float16 f16x8 __attribute__((ext_vector_type(8)));
typedef _Float16 f16x4 __attribute__((ext_vector_type(4)));
typedef float f32x4 __attribute__((ext_vector_type(4)));

#define N_NODES 208
#define NFEAT 8192
#define NHID 8192
#define NCLASS 64

// ---------------- k_adjx: xa = (fp16)(adj @ x) ----------------
// grid (128, 4): blockIdx.x = cb (64 cols), blockIdx.y = rb (52 rows). block 256.
__global__ __launch_bounds__(256) void k_adjx(const float* __restrict__ adj,
                                              const float* __restrict__ x,
                                              _Float16* __restrict__ xa)
{
    __shared__ float xst[64 * 209];   // [c][j], stride 209 (odd -> bank spread)
    const int tid = threadIdx.x;
    const int cb = blockIdx.x, rb = blockIdx.y;
    const int c0 = cb * 64;
    // stage x[0..208)[c0..c0+64) -> xst[c][j]
    for (int i = 0; i < 13; ++i) {
        int idx = tid + i * 256;            // 0..3327 (208 rows * 16 float4)
        int j = idx >> 4, c4 = idx & 15;
        float4 v = *(const float4*)(x + (size_t)j * NFEAT + c0 + c4 * 4);
        xst[(c4*4+0)*209 + j] = v.x;
        xst[(c4*4+1)*209 + j] = v.y;
        xst[(c4*4+2)*209 + j] = v.z;
        xst[(c4*4+3)*209 + j] = v.w;
    }
    __syncthreads();
    const int c  = tid & 63;
    const int rg = __builtin_amdgcn_readfirstlane(tid >> 6); // wave-uniform
    const int r0 = rb * 52 + rg * 13;
    float acc[13];
    #pragma unroll
    for (int i = 0; i < 13; ++i) acc[i] = 0.f;
    for (int j4 = 0; j4 < 52; ++j4) {
        float x0 = xst[c*209 + j4*4 + 0];
        float x1 = xst[c*209 + j4*4 + 1];
        float x2 = xst[c*209 + j4*4 + 2];
        float x3 = xst[c*209 + j4*4 + 3];
        #pragma unroll
        for (int rr = 0; rr < 13; ++rr) {
            float4 a = *(const float4*)(adj + (size_t)(r0 + rr) * N_NODES + j4*4);
            acc[rr] += a.x*x0 + a.y*x1 + a.z*x2 + a.w*x3;
        }
    }
    #pragma unroll
    for (int rr = 0; rr < 13; ++rr)
        xa[(size_t)(r0 + rr) * NFEAT + c0 + c] = (_Float16)acc[rr];
}

// ---------------- k_gemm1: sp[ks] = xa @ W1 (fp16 MFMA, split-K=2) ----------------
// grid (128, 2): x = nblk (64 cols), y = ks. block 512 (8 waves).
__global__ __launch_bounds__(512) void k_gemm1(const _Float16* __restrict__ xa,
                                               const float* __restrict__ w1,
                                               float* __restrict__ sp)
{
    __shared__ _Float16 As[208 * 64];   // [row][k] with XOR swizzle, 26.6 KB
    __shared__ _Float16 Bs[64 * 64];    // [n][k]  with XOR swizzle, 8.2 KB
    const int tid  = threadIdx.x;
    const int nblk = blockIdx.x, ks = blockIdx.y;
    const int lane = tid & 63;
    const int wv = tid >> 6;       // 0..7
    const int ct = wv & 3;         // col tile (16 cols)
    const int rp = wv >> 2;        // row-tile parity
    const int nrt = 7 - rp;        // 7 or 6 row tiles per wave
    const int l15 = lane & 15, lq = lane >> 4;
    const int k0 = ks * 4096;
    const int n0 = nblk * 64;

    f32x4 acc[7];
    #pragma unroll
    for (int i = 0; i < 7; ++i)
        #pragma unroll
        for (int r = 0; r < 4; ++r) acc[i][r] = 0.f;

    uint4 ar[4];
    float br[8];
    const int bn = tid & 63, kg = tid >> 6;

    auto loadAB = [&](int s) {
        const int kk = k0 + s * 64;
        #pragma unroll
        for (int i = 0; i < 4; ++i) {
            int idx = tid + i * 512;
            if (idx < 1664) {                     // 208 rows * 8 16B-chunks
                int row = idx >> 3, k8 = idx & 7;
                ar[i] = *(const uint4*)(xa + (size_t)row * NFEAT + kk + k8 * 8);
            }
        }
        const float* wp = w1 + (size_t)(kk + kg * 8) * NHID + n0 + bn;
        #pragma unroll
        for (int j = 0; j < 8; ++j) br[j] = wp[(size_t)j * NHID];  // coalesced 256B/wave
    };
    auto storeAB = [&]() {
        #pragma unroll
        for (int i = 0; i < 4; ++i) {
            int idx = tid + i * 512;
            if (idx < 1664) {
                int row = idx >> 3, k8 = idx & 7;
                *(uint4*)&As[row * 64 + ((k8 * 8) ^ ((row & 7) * 8))] = ar[i];
            }
        }
        f16x8 bv;
        #pragma unroll
        for (int j = 0; j < 8; ++j) bv[j] = (_Float16)br[j];
        *(f16x8*)&Bs[bn * 64 + ((kg * 8) ^ ((bn & 7) * 8))] = bv;
    };

    loadAB(0);
    for (int s = 0; s < 64; ++s) {
        storeAB();                 // compiler inserts vmcnt waits
        __syncthreads();
        if (s < 63) loadAB(s + 1); // prefetch in flight during compute
        #pragma unroll
        for (int k32 = 0; k32 < 64; k32 += 32) {
            const int koff = k32 + lq * 8;
            const int nn = ct * 16 + l15;
            f16x8 bfrag = *(const f16x8*)&Bs[nn * 64 + (koff ^ ((nn & 7) * 8))];
            #pragma unroll
            for (int i = 0; i < 7; ++i) {
                if (i < nrt) {
                    int row = (rp + 2*i) * 16 + l15;
                    f16x8 afrag = *(const f16x8*)&As[row * 64 + (koff ^ ((row & 7) * 8))];
                    acc[i] = __builtin_amdgcn_mfma_f32_16x16x32_f16(afrag, bfrag, acc[i], 0, 0, 0);
                }
            }
        }
        __syncthreads();
    }
    float* spp = sp + (size_t)ks * N_NODES * NHID;
    #pragma unroll
    for (int i = 0; i < 7; ++i) {
        if (i < nrt) {
            int row0 = (rp + 2*i) * 16 + lq * 4;    // C/D: col=lane&15, row=(lane>>4)*4+reg
            int col  = n0 + ct * 16 + l15;
            #pragma unroll
            for (int r = 0; r < 4; ++r)
                spp[(size_t)(row0 + r) * NHID + col] = acc[i][r];
        }
    }
}

// ---------------- k_h1: h1 = (fp16) relu(sp0 + sp1 + b1) ----------------
__global__ __launch_bounds__(256) void k_h1(const float* __restrict__ sp,
                                            const float* __restrict__ b1,
                                            _Float16* __restrict__ h1)
{
    const size_t e0 = ((size_t)blockIdx.x * 256 + threadIdx.x) * 8;
    const int col = (int)(e0 & (NHID - 1));
    const float* s0 = sp + e0;
    const float* s1 = sp + (size_t)N_NODES * NHID + e0;
    float4 a0 = *(const float4*)(s0), a1 = *(const float4*)(s0 + 4);
    float4 c0 = *(const float4*)(s1), c1 = *(const float4*)(s1 + 4);
    float4 ba = *(const float4*)(b1 + col), bb = *(const float4*)(b1 + col + 4);
    float v[8] = { a0.x+c0.x+ba.x, a0.y+c0.y+ba.y, a0.z+c0.z+ba.z, a0.w+c0.w+ba.w,
                   a1.x+c1.x+bb.x, a1.y+c1.y+bb.y, a1.z+c1.z+bb.z, a1.w+c1.w+bb.w };
    f16x8 h;
    #pragma unroll
    for (int i = 0; i < 8; ++i) h[i] = (_Float16)fmaxf(v[i], 0.f);
    *(f16x8*)(h1 + e0) = h;
}

// ---------------- k_gemm2: s2 += h1 @ W2 (f32, split-K via atomics) ----------------
// grid (32, 4): x = kchunk (256 k), y = rb (52 rows). block 256.
__global__ __launch_bounds__(256) void k_gemm2(const _Float16* __restrict__ h1,
                                               const float* __restrict__ w2,
                                               float* __restrict__ s2)
{
    __shared__ float Wst[64 * 260];   // [c][k]
    __shared__ float H1s[52 * 260];   // [r][k]
    const int tid = threadIdx.x;
    const int kc = blockIdx.x, rb = blockIdx.y;
    const int kk = kc * 256, r0 = rb * 52;
    for (int i = 0; i < 16; ++i) {
        int idx = tid + i * 256;              // 256 k-rows * 16 float4
        int k = idx >> 4, c4 = idx & 15;
        float4 v = *(const float4*)(w2 + (size_t)(kk + k) * NCLASS + c4 * 4);
        Wst[(c4*4+0)*260 + k] = v.x;
        Wst[(c4*4+1)*260 + k] = v.y;
        Wst[(c4*4+2)*260 + k] = v.z;
        Wst[(c4*4+3)*260 + k] = v.w;
    }
    for (int i = 0; i < 13; ++i) {
        int idx = tid + i * 256;              // 52 rows * 64 f16x4
        int r = idx >> 6, k4 = idx & 63;
        f16x4 hv4 = *(const f16x4*)(h1 + (size_t)(r0 + r) * NHID + kk + k4 * 4);
        float4 hv = { (float)hv4[0], (float)hv4[1], (float)hv4[2], (float)hv4[3] };
        *(float4*)&H1s[r * 260 + k4 * 4] = hv;
    }
    __syncthreads();
    const int c  = tid & 63;
    const int rg = __builtin_amdgcn_readfirstlane(tid >> 6);
    float acc[13];
    #pragma unroll
    for (int i = 0; i < 13; ++i) acc[i] = 0.f;
    for (int k4 = 0; k4 < 64; ++k4) {
        float4 wv = *(const float4*)&Wst[c * 260 + k4 * 4];
        #pragma unroll
        for (int rr = 0; rr < 13; ++rr) {
            float4 hv = *(const float4*)&H1s[(rg * 13 + rr) * 260 + k4 * 4];  // uniform -> broadcast
            acc[rr] += hv.x*wv.x + hv.y*wv.y + hv.z*wv.z + hv.w*wv.w;
        }
    }
    #pragma unroll
    for (int rr = 0; rr < 13; ++rr)
        atomicAdd(&s2[(r0 + rg * 13 + rr) * NCLASS + c], acc[rr]);
}

// ---------------- k_h2: h2 = relu(adj @ s2 + b2) ----------------
// grid 26, block 256 (8 rows / block, 2 outputs / thread)
__global__ __launch_bounds__(256) void k_h2(const float* __restrict__ adj,
                                            const float* __restrict__ s2,
                                            const float* __restrict__ b2,
                                            float* __restrict__ h2)
{
    __shared__ float S2s[N_NODES * NCLASS];
    const int tid = threadIdx.x;
    for (int i = 0; i < 13; ++i) {
        int idx = tid + i * 256;              // 3328 float4
        *(float4*)&S2s[idx * 4] = *(const float4*)(s2 + idx * 4);
    }
    __syncthreads();
    const int r0 = blockIdx.x * 8;
    #pragma unroll
    for (int o = 0; o < 2; ++o) {
        int local = tid + o * 256;
        int rr = __builtin_amdgcn_readfirstlane(local >> 6);
        int r = r0 + rr;
        int cc = local & 63;
        float acc = b2[cc];
        for (int j4 = 0; j4 < 52; ++j4) {
            float4 a = *(const float4*)(adj + (size_t)r * N_NODES + j4 * 4);
            acc += a.x * S2s[(j4*4+0)*64 + cc] + a.y * S2s[(j4*4+1)*64 + cc]
                 + a.z * S2s[(j4*4+2)*64 + cc] + a.w * S2s[(j4*4+3)*64 + cc];
        }
        h2[r * 64 + cc] = fmaxf(acc, 0.f);
    }
}

// ---------------- k_fc1: v1 = relu(fc1_w @ h2flat + fc1_b) ----------------
__global__ __launch_bounds__(256) void k_fc1(const float* __restrict__ w,
                                             const float* __restrict__ b,
                                             const float* __restrict__ h2,
                                             float* __restrict__ v1)
{
    __shared__ float vs[13312];
    __shared__ float red[4];
    const int tid = threadIdx.x;
    for (int i = 0; i < 13; ++i) {
        int idx = tid + i * 256;
        *(float4*)&vs[idx * 4] = *(const float4*)(h2 + idx * 4);
    }
    __syncthreads();
    const int row = blockIdx.x;
    float acc = 0.f;
    for (int i = 0; i < 13; ++i) {
        int idx = tid + i * 256;
        float4 wv = *(const float4*)(w + (size_t)row * 13312 + idx * 4);
        float4 hv = *(const float4*)&vs[idx * 4];
        acc += wv.x*hv.x + wv.y*hv.y + wv.z*hv.z + wv.w*hv.w;
    }
    #pragma unroll
    for (int off = 32; off > 0; off >>= 1) acc += __shfl_xor(acc, off, 64);
    if ((tid & 63) == 0) red[tid >> 6] = acc;
    __syncthreads();
    if (tid == 0) v1[row] = fmaxf(red[0] + red[1] + red[2] + red[3] + b[row], 0.f);
}

// ---------------- k_tail: fc2 -> relu -> fc3 -> sigmoid ----------------
__global__ void k_tail(const float* __restrict__ w2, const float* __restrict__ b2,
                       const float* __restrict__ w3, const float* __restrict__ b3,
                       const float* __restrict__ v1, float* __restrict__ out)
{
    __shared__ float v1s[128];
    __shared__ float v2s[32];
    const int tid = threadIdx.x; // 64 threads
    v1s[tid] = v1[tid];
    v1s[tid + 64] = v1[tid + 64];
    __syncthreads();
    if (tid < 32) {
        float acc = b2[tid];
        for (int k = 0; k < 128; ++k) acc += w2[tid * 128 + k] * v1s[k];
        v2s[tid] = fmaxf(acc, 0.f);
    }
    __syncthreads();
    if (tid == 0) {
        float s = b3[0];
        for (int k = 0; k < 32; ++k) s += w3[k] * v2s[k];
        out[0] = 1.f / (1.f + expf(-s));
    }
}

extern "C" void kernel_launch(void* const* d_in, const int* in_sizes, int n_in,
                              void* d_out, int out_size, void* d_ws, size_t ws_size,
                              hipStream_t stream)
{
    const float* x   = (const float*)d_in[0];
    const float* adj = (const float*)d_in[1];
    const float* g1w = (const float*)d_in[2];
    const float* g1b = (const float*)d_in[3];
    const float* g2w = (const float*)d_in[4];
    const float* g2b = (const float*)d_in[5];
    const float* f1w = (const float*)d_in[6];
    const float* f1b = (const float*)d_in[7];
    const float* f2w = (const float*)d_in[8];
    const float* f2b = (const float*)d_in[9];
    const float* f3w = (const float*)d_in[10];
    const float* f3b = (const float*)d_in[11];
    float* out = (float*)d_out;

    char* ws = (char*)d_ws;
    _Float16* xa = (_Float16*)(ws);                 // 208*8192*2  = 3,407,872
    float*    sp = (float*)(ws + 3407872);          // 2*208*8192*4 = 13,631,488
    _Float16* h1 = (_Float16*)(ws + 17039360);      // 3,407,872
    float*    s2 = (float*)(ws + 20447232);         // 53,248
    float*    h2 = (float*)(ws + 20500480);         // 53,248
    float*    v1 = (float*)(ws + 20553728);         // 512

    hipMemsetAsync(s2, 0, N_NODES * NCLASS * sizeof(float), stream);
    k_adjx <<<dim3(128, 4), 256, 0, stream>>>(adj, x, xa);
    k_gemm1<<<dim3(128, 2), 512, 0, stream>>>(xa, g1w, sp);
    k_h1   <<<832, 256, 0, stream>>>(sp, g1b, h1);
    k_gemm2<<<dim3(32, 4), 256, 0, stream>>>(h1, g2w, s2);
    k_h2   <<<26, 256, 0, stream>>>(adj, s2, g2b, h2);
    k_fc1  <<<128, 256, 0, stream>>>(f1w, f1b, h2, v1);
    k_tail <<<1, 64, 0, stream>>>(f2w, f2b, f3w, f3b, v1, out);
}